// Round 15
// baseline (357.279 us; speedup 1.0000x reference)
//
#include <hip/hip_runtime.h>
#include <cstdio>
#include <cstdint>

// RGCN block, aggregation-first (round-14 apex + lane-split k_agg):
//   M[dst, r*256+ch] = mean_{edges (src->dst, rel=r)} x_bf16[src, ch]
//   A = [M | x_bf16]  (50048 x 2304),  B = [W_0..W_7 ; root]  (2304 x 256)
//   h = A @ B + bias  -> BN(batch stats) -> PReLU -> + x
// GEMM: 128x128 tiles, 512 thr (8 waves 2x4), K-step 64, A+B LDS dbuf,
// counted vmcnt(4), bijective XCD-chunk swizzle (measured 120 us).
// Agg: 1 wave per dst; lanes<32 = even edges, lanes>=32 = odd edges; each lane
// loads 16 B (8 ch) -> ONE dwordx4 instruction covers TWO x-rows (2x fewer load
// instrs, 2x ILP vs round-14). Halves combined via shfl_xor(32).
// NOTE: harness delivers integer inputs as int32 (edge_index int64 -> const int*).

constexpr int kN  = 50000;   // nodes
constexpr int kE  = 800000;  // edges
constexpr int kR  = 8;       // relations
constexpr int kC  = 256;     // channels
constexpr int kMP = 50048;   // padded rows (391*128)
constexpr int kK  = 2304;    // GEMM K = 8*256 + 256
constexpr int kWG = (kMP / 128) * (kC / 128);  // 782 grid blocks

// k_conv block ranges
constexpr int kXB = (kN * kC / 4) / 256;            // 12500 x-convert blocks
constexpr int kWB = (kC * kK) / 256;                // 2304 w-convert blocks
constexpr int kPB = ((kMP - kN) * kK / 8) / 256;    // 54 pad-zero blocks (16B units)

typedef __attribute__((ext_vector_type(8))) short bf16x8;
typedef __attribute__((ext_vector_type(4))) float f32x4;
typedef __attribute__((ext_vector_type(2))) unsigned int u32x2;
typedef __attribute__((ext_vector_type(4))) unsigned int u32x4;
typedef __attribute__((ext_vector_type(8))) unsigned short us8;

__device__ __forceinline__ unsigned short f2bf(float f) {
  unsigned u = __builtin_bit_cast(unsigned, f);
  u = u + 0x7FFFu + ((u >> 16) & 1u);
  return (unsigned short)(u >> 16);
}
__device__ __forceinline__ float bf2f(unsigned short s) {
  unsigned u = ((unsigned)s) << 16;
  return __builtin_bit_cast(float, u);
}
__device__ __forceinline__ void gload16(const void* g, void* l) {
  __builtin_amdgcn_global_load_lds((__attribute__((address_space(1))) const void*)g,
                                   (__attribute__((address_space(3))) void*)l, 16, 0, 0);
}

// ---- per-edge counts + packed (dst|rel) records ----
__global__ void k_count(const int* __restrict__ ei, const float* __restrict__ ea,
                        int* __restrict__ cnt, unsigned* __restrict__ pdr) {
  int e = blockIdx.x * blockDim.x + threadIdx.x;
  if (e >= kE) return;
  int dst = ei[kE + e];
  int rel = (int)ea[(size_t)e * 5 + 4];
  if ((unsigned)dst >= (unsigned)kN || (unsigned)rel >= (unsigned)kR) {
    pdr[e] = 0xFFFFFFFFu;
    return;
  }
  pdr[e] = (unsigned)dst | ((unsigned)rel << 16);
  atomicAdd(&cnt[rel * kN + dst], 1);
}

// ---- merged conversions: x->A cols 2048.., W+root->wbfT, A pad rows zero ----
__global__ void k_conv(const float* __restrict__ x, const float* __restrict__ W,
                       const float* __restrict__ root,
                       unsigned short* __restrict__ A, unsigned short* __restrict__ wbfT) {
  int b = blockIdx.x;
  if (b < kXB) {
    int i = (b * 256 + threadIdx.x) * 4;
    int row = i >> 8, col = i & 255;
    float4 v = *(const float4*)(x + i);
    ushort4 o;
    o.x = f2bf(v.x); o.y = f2bf(v.y); o.z = f2bf(v.z); o.w = f2bf(v.w);
    *(ushort4*)(A + (size_t)row * kK + 2048 + col) = o;
  } else if (b < kXB + kWB) {
    int t = (b - kXB) * 256 + threadIdx.x;   // c*kK + k
    int c = t / kK, k = t - c * kK;
    float v;
    if (k < kR * kC) {
      int r = k >> 8, kk = k & 255;
      v = W[(size_t)r * kC * kC + (size_t)kk * kC + c];
    } else {
      v = root[(size_t)(k - kR * kC) * kC + c];
    }
    wbfT[(size_t)c * kK + k] = f2bf(v);
  } else {
    int t = ((b - kXB - kWB) * 256 + threadIdx.x) * 8;   // ushort index into pad region
    u32x2 z = {0u, 0u};
    *(u32x2*)(A + (size_t)kN * kK + t) = z;
  }
}

// ---- group bases: wave-scan of per-dst group sizes + one atomicAdd per wave ----
__global__ void k_grp(const int* __restrict__ cnt, int* __restrict__ cursor,
                      int* __restrict__ off, int* __restrict__ cur) {
  int t = blockIdx.x * blockDim.x + threadIdx.x;
  int lane = threadIdx.x & 63;
  int c[kR];
  int gsz = 0;
  if (t < kN) {
#pragma unroll
    for (int r = 0; r < kR; ++r) { c[r] = cnt[r * kN + t]; gsz += c[r]; }
  } else {
#pragma unroll
    for (int r = 0; r < kR; ++r) c[r] = 0;
  }
  int incl = gsz;
#pragma unroll
  for (int d = 1; d < 64; d <<= 1) {
    int v = __shfl_up(incl, d);
    if (lane >= d) incl += v;
  }
  int wtot = __shfl(incl, 63);
  int base = 0;
  if (lane == 63) base = atomicAdd(cursor, wtot);
  base = __shfl(base, 63);
  if (t < kN) {
    int o = base + incl - gsz;
    off[t] = o;
#pragma unroll
    for (int r = 0; r < kR; ++r) { cur[r * kN + t] = o; o += c[r]; }
  }
}

// ---- fill CSR edge records (u16 src), grouped (dst, rel) ----
__global__ void k_fill(const int* __restrict__ ei, const unsigned* __restrict__ pdr,
                       int* __restrict__ cur, unsigned short* __restrict__ ebuf) {
  int e = blockIdx.x * blockDim.x + threadIdx.x;
  if (e >= kE) return;
  unsigned pd = pdr[e];
  if (pd == 0xFFFFFFFFu) return;
  int dst = pd & 0xFFFF, rel = pd >> 16;
  int pos = atomicAdd(&cur[rel * kN + dst], 1);
  ebuf[pos] = (unsigned short)ei[e];
}

// ---- aggregation: 1 wave per dst, lane-split (even/odd edges x 8-ch lanes) ----
// lane l: half = l>>5 (0: even edges, 1: odd), cidx = l&31 -> channels cidx*8..+7.
// One 16B load per lane = TWO x-rows per wave load instruction.
__global__ __launch_bounds__(256) void k_agg(const unsigned short* __restrict__ ebuf,
                                             const int* __restrict__ off,
                                             const int* __restrict__ cnt,
                                             unsigned short* A) {
  int dst = blockIdx.x * 4 + (threadIdx.x >> 6);
  if (dst >= kN) return;
  int lane = threadIdx.x & 63;
  int half = lane >> 5, cidx = lane & 31;
  int e = off[dst];
  const unsigned short* xcol = A + 2048 + cidx * 8;    // x region of A, this lane's 8 ch
  unsigned short* mrow = A + (size_t)dst * kK + cidx * 8;
#pragma unroll
  for (int r = 0; r < kR; ++r) {
    int c = cnt[r * kN + dst];
    float s[8] = {0.f, 0.f, 0.f, 0.f, 0.f, 0.f, 0.f, 0.f};
    for (int k = 0; k < c; k += 2) {
      bool valid = (k + half) < c;
      int idx = valid ? (e + k + half) : e;            // clamp to a safe slot
      int src = valid ? (int)ebuf[idx] : 0;            // clamp BEFORE address calc
      us8 v = *(const us8*)(xcol + (size_t)src * kK);
      if (valid) {
#pragma unroll
        for (int j = 0; j < 8; ++j) s[j] += bf2f(v[j]);
      }
    }
    e += c;
    // combine even/odd halves: lanes l and l^32 hold partial sums of same channels
#pragma unroll
    for (int j = 0; j < 8; ++j) s[j] += __shfl_xor(s[j], 32);
    float sc = c > 0 ? 1.f / (float)c : 0.f;
    if (half == 0) {
      u32x4 pk;
#pragma unroll
      for (int j = 0; j < 4; ++j)
        pk[j] = (unsigned)f2bf(s[2 * j] * sc) | ((unsigned)f2bf(s[2 * j + 1] * sc) << 16);
      *(u32x4*)(mrow + r * 256) = pk;                  // 32 lanes x 16 B = 512 B row
    }
  }
}

// ---- GEMM [kMP x 2304] @ [2304 x 256] -> d_out f32 (+bias), fused BN column stats ----
// 128x128 per block, 8 waves (2 wm x 4 wn), each wave 64x32 out (acc[4][2]).
// A+B LDS dbuf (64 KB), XOR-swizzled content, counted vmcnt(4), XCD-chunk swizzle.
__global__ __launch_bounds__(512) void k_gemm(const unsigned short* __restrict__ A,
                                              const unsigned short* __restrict__ wbfT,
                                              float* __restrict__ out,
                                              const float* __restrict__ bias,
                                              float* __restrict__ cs,
                                              float* __restrict__ csq) {
  __shared__ __align__(16) unsigned short As[2][128 * 64];  // 2 x 16 KB, swizzled content
  __shared__ __align__(16) unsigned short Bs[2][128 * 64];  // 2 x 16 KB, swizzled content
  const int tid = threadIdx.x;
  const int lane = tid & 63, wv = tid >> 6;
  // bijective XCD-chunk swizzle (nwg=782: q=97, r=6): consecutive wgid -> same XCD,
  // so the 2 N-blocks of each M-row share that XCD's L2 for A.
  const int bid = blockIdx.x;
  const int xcd = bid & 7, idx = bid >> 3;
  const int wgid = (xcd < 6 ? xcd * 98 : 588 + (xcd - 6) * 97) + idx;
  const int n0 = (wgid & 1) * 128, m0 = (wgid >> 1) * 128;
  const int wm = wv >> 2, wn = wv & 3;  // 2x4 wave grid, 64x32 out each
  f32x4 acc[4][2] = {};

  const int lrow = tid >> 3;                            // 0..63 (row base within half-tile)
  const int skk  = ((tid & 7) ^ (lrow & 7)) * 8;        // pre-swizzled global k-chunk

#define STAGE(buf, kt)                                                            \
  {                                                                               \
    const int kb_ = (kt) * 64;                                                    \
    _Pragma("unroll")                                                             \
    for (int c = 0; c < 2; ++c) {                                                 \
      int l_   = tid + 512 * c;       /* 0..1023 */                               \
      int row_ = c * 64 + lrow;       /* 0..127  */                               \
      gload16(A    + (size_t)(m0 + row_) * kK + kb_ + skk, &As[buf][l_ * 8]);     \
      gload16(wbfT + (size_t)(n0 + row_) * kK + kb_ + skk, &Bs[buf][l_ * 8]);     \
    }                                                                             \
  }

  STAGE(0, 0);
  constexpr int NT = kK / 64;  // 36
  for (int t = 0; t < NT; ++t) {
    const int buf = t & 1;
    if (t + 1 < NT) {
      STAGE(buf ^ 1, t + 1);
      asm volatile("s_waitcnt vmcnt(4)" ::: "memory");   // own tile-t loads retired; t+1 in flight
    } else {
      asm volatile("s_waitcnt vmcnt(0)" ::: "memory");
    }
    __builtin_amdgcn_s_barrier();
    __builtin_amdgcn_sched_barrier(0);
#pragma unroll
    for (int kk = 0; kk < 64; kk += 32) {
      const int koff = kk + (lane >> 4) * 8;
      bf16x8 a[4], b[2];
#pragma unroll
      for (int i = 0; i < 4; ++i) {
        int ra = wm * 64 + i * 16 + (lane & 15);
        unsigned ba = (unsigned)(koff * 2) ^ (unsigned)((ra & 7) << 4);
        a[i] = *(const bf16x8*)((const char*)As[buf] + ra * 128 + ba);
      }
#pragma unroll
      for (int j = 0; j < 2; ++j) {
        int rb = wn * 32 + j * 16 + (lane & 15);
        unsigned bb = (unsigned)(koff * 2) ^ (unsigned)((rb & 7) << 4);
        b[j] = *(const bf16x8*)((const char*)Bs[buf] + rb * 128 + bb);
      }
#pragma unroll
      for (int i = 0; i < 4; ++i)
#pragma unroll
        for (int j = 0; j < 2; ++j)
          acc[i][j] = __builtin_amdgcn_mfma_f32_16x16x32_bf16(a[i], b[j], acc[i][j], 0, 0, 0);
    }
    __builtin_amdgcn_s_barrier();            // compute done before next stage overwrites buf
    __builtin_amdgcn_sched_barrier(0);
  }
#undef STAGE

  // C/D layout: col = lane&15, row = (lane>>4)*4 + q.  Stats on raw acc (bias-free;
  // pad rows have zero acc so they contribute nothing to the sums).
#pragma unroll
  for (int j = 0; j < 2; ++j) {
    int col = n0 + wn * 32 + j * 16 + (lane & 15);
    float bv = bias[col];
    float s = 0.f, ss = 0.f;
#pragma unroll
    for (int i = 0; i < 4; ++i) {
      int rb = m0 + wm * 64 + i * 16 + (lane >> 4) * 4;
#pragma unroll
      for (int q = 0; q < 4; ++q) {
        float v = acc[i][j][q];
        s += v; ss += v * v;
        int row = rb + q;
        if (row < kN) out[(size_t)row * kC + col] = v + bv;
      }
    }
    s  += __shfl_xor(s, 16);  s  += __shfl_xor(s, 32);
    ss += __shfl_xor(ss, 16); ss += __shfl_xor(ss, 32);
    if (lane < 16) { atomicAdd(&cs[col], s); atomicAdd(&csq[col], ss); }
  }
}

// ---- BN normalize + PReLU + residual (stats are bias-free; shift mu by bias) ----
__global__ void k_final(float* __restrict__ h, const float* __restrict__ x,
                        const float* __restrict__ cs, const float* __restrict__ csq,
                        const float* __restrict__ bias,
                        const float* __restrict__ gamma, const float* __restrict__ beta,
                        const float* __restrict__ prelu) {
  int idx = (blockIdx.x * blockDim.x + threadIdx.x) * 4;
  if (idx >= kN * kC) return;
  int col = idx & 255;
  const float inv_n = 1.0f / (float)kN;
  float a = prelu[0];
  float4 hv = *(float4*)(h + idx);
  float4 xv = *(const float4*)(x + idx);
  float hr[4] = {hv.x, hv.y, hv.z, hv.w};
  float xr[4] = {xv.x, xv.y, xv.z, xv.w};
#pragma unroll
  for (int j = 0; j < 4; ++j) {
    int c = col + j;
    float mu_raw = cs[c] * inv_n;
    float var = csq[c] * inv_n - mu_raw * mu_raw;
    float mu  = mu_raw + bias[c];          // h was stored with bias added
    float k   = gamma[c] * rsqrtf(var + 1e-5f);
    float v   = (hr[j] - mu) * k + beta[c];
    v = v > 0.f ? v : a * v;
    hr[j] = v + xr[j];
  }
  *(float4*)(h + idx) = make_float4(hr[0], hr[1], hr[2], hr[3]);
}

extern "C" void kernel_launch(void* const* d_in, const int* in_sizes, int n_in,
                              void* d_out, int out_size, void* d_ws, size_t ws_size,
                              hipStream_t stream) {
  const float* x     = (const float*)d_in[0];
  const int*   ei    = (const int*)d_in[1];     // int64 in ref -> int32 from harness
  const float* ea    = (const float*)d_in[2];
  const float* W     = (const float*)d_in[3];
  const float* root  = (const float*)d_in[4];
  const float* bias  = (const float*)d_in[5];
  const float* gamma = (const float*)d_in[6];
  const float* beta  = (const float*)d_in[7];
  const float* prelu = (const float*)d_in[8];
  float* out = (float*)d_out;
  char* ws = (char*)d_ws;

  size_t o = 0;
  auto alloc = [&](size_t sz) { size_t r = o; o += (sz + 255) & ~(size_t)255; return r; };
  size_t a_o    = alloc((size_t)kMP * kK * 2);       // 230.6 MB
  size_t wbf_o  = alloc((size_t)kC * kK * 2);        // 1.2 MB
  size_t cnt_o  = alloc((size_t)kR * kN * 4);        // 1.6 MB
  size_t cs_o   = alloc(256 * 4);
  size_t csq_o  = alloc(256 * 4);
  size_t csr_o  = alloc(256);                        // global cursor (1 int)
  size_t zend   = o;                                 // end of must-zero region
  size_t off_o  = alloc((size_t)kN * 4);
  size_t cur_o  = alloc((size_t)kR * kN * 4);
  size_t eb_o   = alloc((size_t)kE * 2);             // u16 src records
  size_t pdr_o  = alloc((size_t)kE * 4);             // packed dst|rel<<16
  if (o > ws_size) {
    fprintf(stderr, "[RGCN kernel] ws too small: need %zu have %zu\n", o, ws_size);
    return;
  }

  unsigned short* A    = (unsigned short*)(ws + a_o);
  unsigned short* wbfT = (unsigned short*)(ws + wbf_o);
  int*      cnt    = (int*)(ws + cnt_o);
  float*    cs     = (float*)(ws + cs_o);
  float*    csq    = (float*)(ws + csq_o);
  int*      cursor = (int*)(ws + csr_o);
  int*      offp   = (int*)(ws + off_o);
  int*      cur    = (int*)(ws + cur_o);
  unsigned short* ebuf = (unsigned short*)(ws + eb_o);
  unsigned* pdr    = (unsigned*)(ws + pdr_o);

  hipMemsetAsync(ws + cnt_o, 0, zend - cnt_o, stream);           // cnt/cs/csq/cursor
  k_count<<<(kE + 255) / 256, 256, 0, stream>>>(ei, ea, cnt, pdr);
  k_conv<<<kXB + kWB + kPB, 256, 0, stream>>>(x, W, root, A, wbfT);
  k_grp<<<(kN + 255) / 256, 256, 0, stream>>>(cnt, cursor, offp, cur);
  k_fill<<<(kE + 255) / 256, 256, 0, stream>>>(ei, pdr, cur, ebuf);
  k_agg<<<(kN + 3) / 4, 256, 0, stream>>>(ebuf, offp, cnt, A);
  k_gemm<<<kWG, 512, 0, stream>>>(A, wbfT, out, bias, cs, csq);
  k_final<<<(kN * kC / 4) / 256, 256, 0, stream>>>(out, x, cs, csq, bias, gamma, beta, prelu);
}

// Round 16
// 334.360 us; speedup vs baseline: 1.0685x; 1.0685x over previous
//
#include <hip/hip_runtime.h>
#include <cstdio>
#include <cstdint>

// RGCN block, aggregation-first (round-14 apex + k_count merged into k_prep):
//   M[dst, r*256+ch] = mean_{edges (src->dst, rel=r)} x_bf16[src, ch]
//   A = [M | x_bf16]  (50048 x 2304),  B = [W_0..W_7 ; root]  (2304 x 256)
//   h = A @ B + bias  -> BN(batch stats) -> PReLU -> + x
// GEMM: 128x128 tiles, 512 thr (8 waves 2x4), K-step 64, A+B LDS dbuf,
// counted vmcnt(4), bijective XCD-chunk swizzle (measured 120 us).
// Agg: 1 wave per dst, 2-wide unrolled edge loads (round-14 measured best;
// round-15 lane-split regressed: avg group = 2 edges, fixed cost dominates).
// k_prep merges edge-count+pdr-pack, x-convert, W-convert, A-pad-zero
// (all independent) into ONE dispatch.
// NOTE: harness delivers integer inputs as int32 (edge_index int64 -> const int*).

constexpr int kN  = 50000;   // nodes
constexpr int kE  = 800000;  // edges
constexpr int kR  = 8;       // relations
constexpr int kC  = 256;     // channels
constexpr int kMP = 50048;   // padded rows (391*128)
constexpr int kK  = 2304;    // GEMM K = 8*256 + 256
constexpr int kWG = (kMP / 128) * (kC / 128);  // 782 grid blocks

// k_prep block ranges
constexpr int kCB = (kE + 255) / 256;               // 3125 edge-count blocks
constexpr int kXB = (kN * kC / 4) / 256;            // 12500 x-convert blocks
constexpr int kWB = (kC * kK) / 256;                // 2304 w-convert blocks
constexpr int kPB = ((kMP - kN) * kK / 8) / 256;    // 54 pad-zero blocks (16B units)

typedef __attribute__((ext_vector_type(8))) short bf16x8;
typedef __attribute__((ext_vector_type(4))) float f32x4;
typedef __attribute__((ext_vector_type(2))) unsigned int u32x2;

__device__ __forceinline__ unsigned short f2bf(float f) {
  unsigned u = __builtin_bit_cast(unsigned, f);
  u = u + 0x7FFFu + ((u >> 16) & 1u);
  return (unsigned short)(u >> 16);
}
__device__ __forceinline__ float bf2f(unsigned short s) {
  unsigned u = ((unsigned)s) << 16;
  return __builtin_bit_cast(float, u);
}
__device__ __forceinline__ void gload16(const void* g, void* l) {
  __builtin_amdgcn_global_load_lds((__attribute__((address_space(1))) const void*)g,
                                   (__attribute__((address_space(3))) void*)l, 16, 0, 0);
}

// ---- merged prep: edge counts + pdr pack | x->A cols 2048.. | W+root->wbfT | A pad zero ----
__global__ void k_prep(const int* __restrict__ ei, const float* __restrict__ ea,
                       const float* __restrict__ x, const float* __restrict__ W,
                       const float* __restrict__ root,
                       int* __restrict__ cnt, unsigned* __restrict__ pdr,
                       unsigned short* __restrict__ A, unsigned short* __restrict__ wbfT) {
  int b = blockIdx.x;
  if (b < kCB) {
    int e = b * 256 + threadIdx.x;
    if (e >= kE) return;
    int dst = ei[kE + e];
    int rel = (int)ea[(size_t)e * 5 + 4];
    if ((unsigned)dst >= (unsigned)kN || (unsigned)rel >= (unsigned)kR) {
      pdr[e] = 0xFFFFFFFFu;
      return;
    }
    pdr[e] = (unsigned)dst | ((unsigned)rel << 16);
    atomicAdd(&cnt[rel * kN + dst], 1);
  } else if (b < kCB + kXB) {
    int i = ((b - kCB) * 256 + threadIdx.x) * 4;
    int row = i >> 8, col = i & 255;
    float4 v = *(const float4*)(x + i);
    ushort4 o;
    o.x = f2bf(v.x); o.y = f2bf(v.y); o.z = f2bf(v.z); o.w = f2bf(v.w);
    *(ushort4*)(A + (size_t)row * kK + 2048 + col) = o;
  } else if (b < kCB + kXB + kWB) {
    int t = (b - kCB - kXB) * 256 + threadIdx.x;   // c*kK + k
    int c = t / kK, k = t - c * kK;
    float v;
    if (k < kR * kC) {
      int r = k >> 8, kk = k & 255;
      v = W[(size_t)r * kC * kC + (size_t)kk * kC + c];
    } else {
      v = root[(size_t)(k - kR * kC) * kC + c];
    }
    wbfT[(size_t)c * kK + k] = f2bf(v);
  } else {
    int t = ((b - kCB - kXB - kWB) * 256 + threadIdx.x) * 8;   // ushort idx into pad region
    u32x2 z = {0u, 0u};
    *(u32x2*)(A + (size_t)kN * kK + t) = z;
  }
}

// ---- group bases: wave-scan of per-dst group sizes + one atomicAdd per wave ----
__global__ void k_grp(const int* __restrict__ cnt, int* __restrict__ cursor,
                      int* __restrict__ off, int* __restrict__ cur) {
  int t = blockIdx.x * blockDim.x + threadIdx.x;
  int lane = threadIdx.x & 63;
  int c[kR];
  int gsz = 0;
  if (t < kN) {
#pragma unroll
    for (int r = 0; r < kR; ++r) { c[r] = cnt[r * kN + t]; gsz += c[r]; }
  } else {
#pragma unroll
    for (int r = 0; r < kR; ++r) c[r] = 0;
  }
  int incl = gsz;
#pragma unroll
  for (int d = 1; d < 64; d <<= 1) {
    int v = __shfl_up(incl, d);
    if (lane >= d) incl += v;
  }
  int wtot = __shfl(incl, 63);
  int base = 0;
  if (lane == 63) base = atomicAdd(cursor, wtot);
  base = __shfl(base, 63);
  if (t < kN) {
    int o = base + incl - gsz;
    off[t] = o;
#pragma unroll
    for (int r = 0; r < kR; ++r) { cur[r * kN + t] = o; o += c[r]; }
  }
}

// ---- fill CSR edge records (u16 src), grouped (dst, rel) ----
__global__ void k_fill(const int* __restrict__ ei, const unsigned* __restrict__ pdr,
                       int* __restrict__ cur, unsigned short* __restrict__ ebuf) {
  int e = blockIdx.x * blockDim.x + threadIdx.x;
  if (e >= kE) return;
  unsigned pd = pdr[e];
  if (pd == 0xFFFFFFFFu) return;
  int dst = pd & 0xFFFF, rel = pd >> 16;
  int pos = atomicAdd(&cur[rel * kN + dst], 1);
  ebuf[pos] = (unsigned short)ei[e];
}

// ---- aggregation: 1 wave per dst; mean x[src] per relation -> A cols 0..2047 (NT) ----
// 2-wide unrolled edge loads: two independent row loads per iter, adds kept
// in order -> bit-identical to the serial loop. (round-14 measured best)
__global__ __launch_bounds__(256) void k_agg(const unsigned short* __restrict__ ebuf,
                                             const int* __restrict__ off,
                                             const int* __restrict__ cnt,
                                             unsigned short* A) {
  int dst = blockIdx.x * 4 + (threadIdx.x >> 6);
  if (dst >= kN) return;
  int lane = threadIdx.x & 63;
  int e = off[dst];
  const unsigned short* xcols = A + 2048 + lane * 4;   // x region of A
  unsigned short* mrow = A + (size_t)dst * kK + lane * 4;
#pragma unroll
  for (int r = 0; r < kR; ++r) {
    int c = cnt[r * kN + dst];
    float s0 = 0.f, s1 = 0.f, s2 = 0.f, s3 = 0.f;
    int k = 0;
    for (; k + 2 <= c; k += 2) {
      int ia = ebuf[e + k], ib = ebuf[e + k + 1];
      ushort4 va = *(const ushort4*)(xcols + (size_t)ia * kK);
      ushort4 vb = *(const ushort4*)(xcols + (size_t)ib * kK);
      s0 += bf2f(va.x); s1 += bf2f(va.y); s2 += bf2f(va.z); s3 += bf2f(va.w);
      s0 += bf2f(vb.x); s1 += bf2f(vb.y); s2 += bf2f(vb.z); s3 += bf2f(vb.w);
    }
    if (k < c) {
      int ia = ebuf[e + k];
      ushort4 va = *(const ushort4*)(xcols + (size_t)ia * kK);
      s0 += bf2f(va.x); s1 += bf2f(va.y); s2 += bf2f(va.z); s3 += bf2f(va.w);
    }
    e += c;
    float sc = c > 0 ? 1.f / (float)c : 0.f;
    unsigned lo = (unsigned)f2bf(s0 * sc) | ((unsigned)f2bf(s1 * sc) << 16);
    unsigned hi = (unsigned)f2bf(s2 * sc) | ((unsigned)f2bf(s3 * sc) << 16);
    u32x2 pk = {lo, hi};
    __builtin_nontemporal_store(pk, (u32x2*)(mrow + r * 256));
  }
}

// ---- GEMM [kMP x 2304] @ [2304 x 256] -> d_out f32 (+bias), fused BN column stats ----
// 128x128 per block, 8 waves (2 wm x 4 wn), each wave 64x32 out (acc[4][2]).
// A+B LDS dbuf (64 KB), XOR-swizzled content, counted vmcnt(4), XCD-chunk swizzle.
__global__ __launch_bounds__(512) void k_gemm(const unsigned short* __restrict__ A,
                                              const unsigned short* __restrict__ wbfT,
                                              float* __restrict__ out,
                                              const float* __restrict__ bias,
                                              float* __restrict__ cs,
                                              float* __restrict__ csq) {
  __shared__ __align__(16) unsigned short As[2][128 * 64];  // 2 x 16 KB, swizzled content
  __shared__ __align__(16) unsigned short Bs[2][128 * 64];  // 2 x 16 KB, swizzled content
  const int tid = threadIdx.x;
  const int lane = tid & 63, wv = tid >> 6;
  // bijective XCD-chunk swizzle (nwg=782: q=97, r=6): consecutive wgid -> same XCD,
  // so the 2 N-blocks of each M-row share that XCD's L2 for A.
  const int bid = blockIdx.x;
  const int xcd = bid & 7, idx = bid >> 3;
  const int wgid = (xcd < 6 ? xcd * 98 : 588 + (xcd - 6) * 97) + idx;
  const int n0 = (wgid & 1) * 128, m0 = (wgid >> 1) * 128;
  const int wm = wv >> 2, wn = wv & 3;  // 2x4 wave grid, 64x32 out each
  f32x4 acc[4][2] = {};

  const int lrow = tid >> 3;                            // 0..63 (row base within half-tile)
  const int skk  = ((tid & 7) ^ (lrow & 7)) * 8;        // pre-swizzled global k-chunk

#define STAGE(buf, kt)                                                            \
  {                                                                               \
    const int kb_ = (kt) * 64;                                                    \
    _Pragma("unroll")                                                             \
    for (int c = 0; c < 2; ++c) {                                                 \
      int l_   = tid + 512 * c;       /* 0..1023 */                               \
      int row_ = c * 64 + lrow;       /* 0..127  */                               \
      gload16(A    + (size_t)(m0 + row_) * kK + kb_ + skk, &As[buf][l_ * 8]);     \
      gload16(wbfT + (size_t)(n0 + row_) * kK + kb_ + skk, &Bs[buf][l_ * 8]);     \
    }                                                                             \
  }

  STAGE(0, 0);
  constexpr int NT = kK / 64;  // 36
  for (int t = 0; t < NT; ++t) {
    const int buf = t & 1;
    if (t + 1 < NT) {
      STAGE(buf ^ 1, t + 1);
      asm volatile("s_waitcnt vmcnt(4)" ::: "memory");   // own tile-t loads retired; t+1 in flight
    } else {
      asm volatile("s_waitcnt vmcnt(0)" ::: "memory");
    }
    __builtin_amdgcn_s_barrier();
    __builtin_amdgcn_sched_barrier(0);
#pragma unroll
    for (int kk = 0; kk < 64; kk += 32) {
      const int koff = kk + (lane >> 4) * 8;
      bf16x8 a[4], b[2];
#pragma unroll
      for (int i = 0; i < 4; ++i) {
        int ra = wm * 64 + i * 16 + (lane & 15);
        unsigned ba = (unsigned)(koff * 2) ^ (unsigned)((ra & 7) << 4);
        a[i] = *(const bf16x8*)((const char*)As[buf] + ra * 128 + ba);
      }
#pragma unroll
      for (int j = 0; j < 2; ++j) {
        int rb = wn * 32 + j * 16 + (lane & 15);
        unsigned bb = (unsigned)(koff * 2) ^ (unsigned)((rb & 7) << 4);
        b[j] = *(const bf16x8*)((const char*)Bs[buf] + rb * 128 + bb);
      }
#pragma unroll
      for (int i = 0; i < 4; ++i)
#pragma unroll
        for (int j = 0; j < 2; ++j)
          acc[i][j] = __builtin_amdgcn_mfma_f32_16x16x32_bf16(a[i], b[j], acc[i][j], 0, 0, 0);
    }
    __builtin_amdgcn_s_barrier();            // compute done before next stage overwrites buf
    __builtin_amdgcn_sched_barrier(0);
  }
#undef STAGE

  // C/D layout: col = lane&15, row = (lane>>4)*4 + q.  Stats on raw acc (bias-free;
  // pad rows have zero acc so they contribute nothing to the sums).
#pragma unroll
  for (int j = 0; j < 2; ++j) {
    int col = n0 + wn * 32 + j * 16 + (lane & 15);
    float bv = bias[col];
    float s = 0.f, ss = 0.f;
#pragma unroll
    for (int i = 0; i < 4; ++i) {
      int rb = m0 + wm * 64 + i * 16 + (lane >> 4) * 4;
#pragma unroll
      for (int q = 0; q < 4; ++q) {
        float v = acc[i][j][q];
        s += v; ss += v * v;
        int row = rb + q;
        if (row < kN) out[(size_t)row * kC + col] = v + bv;
      }
    }
    s  += __shfl_xor(s, 16);  s  += __shfl_xor(s, 32);
    ss += __shfl_xor(ss, 16); ss += __shfl_xor(ss, 32);
    if (lane < 16) { atomicAdd(&cs[col], s); atomicAdd(&csq[col], ss); }
  }
}

// ---- BN normalize + PReLU + residual (stats are bias-free; shift mu by bias) ----
__global__ void k_final(float* __restrict__ h, const float* __restrict__ x,
                        const float* __restrict__ cs, const float* __restrict__ csq,
                        const float* __restrict__ bias,
                        const float* __restrict__ gamma, const float* __restrict__ beta,
                        const float* __restrict__ prelu) {
  int idx = (blockIdx.x * blockDim.x + threadIdx.x) * 4;
  if (idx >= kN * kC) return;
  int col = idx & 255;
  const float inv_n = 1.0f / (float)kN;
  float a = prelu[0];
  float4 hv = *(float4*)(h + idx);
  float4 xv = *(const float4*)(x + idx);
  float hr[4] = {hv.x, hv.y, hv.z, hv.w};
  float xr[4] = {xv.x, xv.y, xv.z, xv.w};
#pragma unroll
  for (int j = 0; j < 4; ++j) {
    int c = col + j;
    float mu_raw = cs[c] * inv_n;
    float var = csq[c] * inv_n - mu_raw * mu_raw;
    float mu  = mu_raw + bias[c];          // h was stored with bias added
    float k   = gamma[c] * rsqrtf(var + 1e-5f);
    float v   = (hr[j] - mu) * k + beta[c];
    v = v > 0.f ? v : a * v;
    hr[j] = v + xr[j];
  }
  *(float4*)(h + idx) = make_float4(hr[0], hr[1], hr[2], hr[3]);
}

extern "C" void kernel_launch(void* const* d_in, const int* in_sizes, int n_in,
                              void* d_out, int out_size, void* d_ws, size_t ws_size,
                              hipStream_t stream) {
  const float* x     = (const float*)d_in[0];
  const int*   ei    = (const int*)d_in[1];     // int64 in ref -> int32 from harness
  const float* ea    = (const float*)d_in[2];
  const float* W     = (const float*)d_in[3];
  const float* root  = (const float*)d_in[4];
  const float* bias  = (const float*)d_in[5];
  const float* gamma = (const float*)d_in[6];
  const float* beta  = (const float*)d_in[7];
  const float* prelu = (const float*)d_in[8];
  float* out = (float*)d_out;
  char* ws = (char*)d_ws;

  size_t o = 0;
  auto alloc = [&](size_t sz) { size_t r = o; o += (sz + 255) & ~(size_t)255; return r; };
  size_t a_o    = alloc((size_t)kMP * kK * 2);       // 230.6 MB
  size_t wbf_o  = alloc((size_t)kC * kK * 2);        // 1.2 MB
  size_t cnt_o  = alloc((size_t)kR * kN * 4);        // 1.6 MB
  size_t cs_o   = alloc(256 * 4);
  size_t csq_o  = alloc(256 * 4);
  size_t csr_o  = alloc(256);                        // global cursor (1 int)
  size_t zend   = o;                                 // end of must-zero region
  size_t off_o  = alloc((size_t)kN * 4);
  size_t cur_o  = alloc((size_t)kR * kN * 4);
  size_t eb_o   = alloc((size_t)kE * 2);             // u16 src records
  size_t pdr_o  = alloc((size_t)kE * 4);             // packed dst|rel<<16
  if (o > ws_size) {
    fprintf(stderr, "[RGCN kernel] ws too small: need %zu have %zu\n", o, ws_size);
    return;
  }

  unsigned short* A    = (unsigned short*)(ws + a_o);
  unsigned short* wbfT = (unsigned short*)(ws + wbf_o);
  int*      cnt    = (int*)(ws + cnt_o);
  float*    cs     = (float*)(ws + cs_o);
  float*    csq    = (float*)(ws + csq_o);
  int*      cursor = (int*)(ws + csr_o);
  int*      offp   = (int*)(ws + off_o);
  int*      cur    = (int*)(ws + cur_o);
  unsigned short* ebuf = (unsigned short*)(ws + eb_o);
  unsigned* pdr    = (unsigned*)(ws + pdr_o);

  hipMemsetAsync(ws + cnt_o, 0, zend - cnt_o, stream);           // cnt/cs/csq/cursor
  k_prep<<<kCB + kXB + kWB + kPB, 256, 0, stream>>>(ei, ea, x, W, root, cnt, pdr, A, wbfT);
  k_grp<<<(kN + 255) / 256, 256, 0, stream>>>(cnt, cursor, offp, cur);
  k_fill<<<(kE + 255) / 256, 256, 0, stream>>>(ei, pdr, cur, ebuf);
  k_agg<<<(kN + 3) / 4, 256, 0, stream>>>(ebuf, offp, cnt, A);
  k_gemm<<<kWG, 512, 0, stream>>>(A, wbfT, out, bias, cs, csq);
  k_final<<<(kN * kC / 4) / 256, 256, 0, stream>>>(out, x, cs, csq, bias, gamma, beta, prelu);
}